// Round 6
// baseline (245.217 us; speedup 1.0000x reference)
//
#include <hip/hip_runtime.h>
#include <hip/hip_bf16.h>

typedef __attribute__((ext_vector_type(8))) short short8;
typedef __attribute__((ext_vector_type(4))) short short4v;
typedef __attribute__((ext_vector_type(4))) float f32x4;
typedef __attribute__((ext_vector_type(2))) unsigned int u32x2;

#define S_LEN 2048
#define DM 768
#define NH 12
#define HD 64
#define NB 2
#define MROWS (NB*S_LEN)          // 4096
#define NEGINF (-1.0e9f)
#define XEL 3145728               // 4096*768 elements
#define WEL 589824                // 768*768

__device__ __forceinline__ unsigned short f2bf(float x) {
    __hip_bfloat16 h = __float2bfloat16(x);   // RNE; compiler pairs into v_cvt_pk_bf16_f32
    return *reinterpret_cast<unsigned short*>(&h);
}

// async global->LDS, 16B per lane (wave-uniform base + lane*16 matches linear dest).
__device__ __forceinline__ void gl_lds16(const unsigned short* g, unsigned short* l) {
    __builtin_amdgcn_global_load_lds(
        (const __attribute__((address_space(1))) unsigned int*)g,
        (__attribute__((address_space(3))) unsigned int*)l, 16, 0, 0);
}

// ---------------- weights fp32 -> bf16 (+ zero the attn work queues) ----------------
__global__ __launch_bounds__(256) void cvt_w_kernel(
    const float* w0, const float* w1, const float* w2, const float* w3,
    unsigned short* dst, int* cnts)
{
    int which = blockIdx.y;
    const float* src = (which == 0) ? w0 : (which == 1) ? w1 : (which == 2) ? w2 : w3;
    size_t idx = (size_t)blockIdx.x * 256 + threadIdx.x;   // 0 .. WEL/8-1
    const float* s = src + idx * 8;
    f32x4 v0 = *(const f32x4*)s;
    f32x4 v1 = *(const f32x4*)(s + 4);
    short8 o;
    o[0] = (short)f2bf(v0[0]); o[1] = (short)f2bf(v0[1]);
    o[2] = (short)f2bf(v0[2]); o[3] = (short)f2bf(v0[3]);
    o[4] = (short)f2bf(v1[0]); o[5] = (short)f2bf(v1[1]);
    o[6] = (short)f2bf(v1[2]); o[7] = (short)f2bf(v1[3]);
    *(short8*)&dst[(size_t)which * WEL + idx * 8] = o;
    if (which == 0 && blockIdx.x == 0 && threadIdx.x < 128) cnts[threadIdx.x] = 0;
}

// ---------------- QKV projection: C = X @ W^T + b, fused fp32->bf16 A-staging ----------------
// BM=128, BN=128. grid (192, 3). by 0 -> q (pre-scaled by 0.125); by 1 -> k; by 2 -> vt.
__global__ __launch_bounds__(256) void gemm_qkv_kernel(
    const float* Xq, const float* Xk, const float* Xv, const unsigned short* Wall,
    const float* b0, const float* b1, const float* b2, unsigned short* qh)
{
    int by = blockIdx.y;
    const float* A = (by == 0) ? Xq : (by == 1) ? Xk : Xv;
    const unsigned short* W = Wall + (size_t)by * WEL;
    const float* bias = (by == 0) ? b0 : (by == 1) ? b1 : b2;
    int bid = blockIdx.x;
    int im = bid & 31;      // 32 M tiles of 128
    int jn = bid >> 5;      // 6 N tiles of 128
    int i0 = im * 128, j0 = jn * 128;

    __shared__ unsigned short As[128 * 64];   // 16KB
    __shared__ unsigned short Ws[128 * 64];   // 16KB

    int t = threadIdx.x;
    int w = t >> 6, lane = t & 63, g = lane >> 4, fr = lane & 15;
    int wm = w >> 1, wn = w & 1;              // wave tile 64 x 64

    f32x4 acc[4][4];
    for (int i = 0; i < 4; ++i)
        for (int j = 0; j < 4; ++j)
            acc[i][j] = (f32x4){0.f, 0.f, 0.f, 0.f};

    int boff = t * 16;          // W staging byte offset per 4KB round
    int arow = t >> 3;          // A staging: 32 rows/round, 8 threads/row
    int acol = (t & 7) * 8;     // 8 floats per thread

    for (int k0 = 0; k0 < DM; k0 += 64) {
        __syncthreads();
        // W: async global->LDS bf16 (4 x 4KB rounds)
        for (int r = 0; r < 4; ++r) {
            int b = r * 4096 + boff;
            int row = b >> 7, colb = b & 127;
            gl_lds16(&W[(size_t)(j0 + row) * DM + k0 + (colb >> 1)],
                     (unsigned short*)((char*)Ws + b));
        }
        // A: reg-staged fp32 -> bf16 (4 x 32-row rounds)
        for (int rr = 0; rr < 4; ++rr) {
            int row = rr * 32 + arow;
            const float* src = &A[(size_t)(i0 + row) * DM + k0 + acol];
            f32x4 v0 = *(const f32x4*)src;
            f32x4 v1 = *(const f32x4*)(src + 4);
            short8 o;
            o[0] = (short)f2bf(v0[0]); o[1] = (short)f2bf(v0[1]);
            o[2] = (short)f2bf(v0[2]); o[3] = (short)f2bf(v0[3]);
            o[4] = (short)f2bf(v1[0]); o[5] = (short)f2bf(v1[1]);
            o[6] = (short)f2bf(v1[2]); o[7] = (short)f2bf(v1[3]);
            *(short8*)&As[row * 64 + acol] = o;
        }
        __syncthreads();
        for (int kk = 0; kk < 2; ++kk) {
            short8 af[4], wf[4];
            for (int it = 0; it < 4; ++it)
                af[it] = *(const short8*)&As[(wm * 64 + it * 16 + fr) * 64 + kk * 32 + g * 8];
            for (int jt = 0; jt < 4; ++jt)
                wf[jt] = *(const short8*)&Ws[(wn * 64 + jt * 16 + fr) * 64 + kk * 32 + g * 8];
            for (int it = 0; it < 4; ++it)
                for (int jt = 0; jt < 4; ++jt)
                    acc[it][jt] = __builtin_amdgcn_mfma_f32_16x16x32_bf16(af[it], wf[jt], acc[it][jt], 0, 0, 0);
        }
    }

    float scl = (by == 0) ? 0.125f : 1.0f;    // fold 1/sqrt(64) into q (exact)
    if (by < 2) {
        unsigned short* outp = qh + (size_t)by * XEL;   // head-split [b][h][s][64]
        for (int jt = 0; jt < 4; ++jt) {
            int j = j0 + wn * 64 + jt * 16 + fr;
            float bv = bias[j];
            int h = j >> 6, dq = j & 63;
            for (int it = 0; it < 4; ++it)
                for (int r = 0; r < 4; ++r) {
                    int i = i0 + wm * 64 + it * 16 + g * 4 + r;
                    int bb = i >> 11, s = i & 2047;
                    outp[((size_t)((bb * NH + h) * S_LEN) + s) * HD + dq] = f2bf((acc[it][jt][r] + bv) * scl);
                }
        }
    } else {
        unsigned short* vtp = qh + (size_t)2 * XEL;     // V transposed [bh][64][s]
        for (int jt = 0; jt < 4; ++jt) {
            int j = j0 + wn * 64 + jt * 16 + fr;
            float bv = bias[j];
            int h = j >> 6, dq = j & 63;
            for (int it = 0; it < 4; ++it) {
                int ibase = i0 + wm * 64 + it * 16 + g * 4;
                int bb = ibase >> 11, s = ibase & 2047;
                short4v o;
                for (int r = 0; r < 4; ++r) o[r] = (short)f2bf(acc[it][jt][r] + bv);
                *(short4v*)&vtp[((size_t)(bb * NH + h) * HD + dq) * S_LEN + s] = o;
            }
        }
    }
}

// ---------------- out projection: BM=64, BN=64, 768 blocks (3/CU) ----------------
__global__ __launch_bounds__(256) void gemm_o_kernel(
    const unsigned short* A, const unsigned short* W, const float* bias, float* f_out)
{
    int bid = blockIdx.x;
    int im = bid & 63;      // 64 M tiles of 64
    int jn = bid >> 6;      // 12 N tiles of 64
    int i0 = im * 64, j0 = jn * 64;

    __shared__ unsigned short As[64 * 64];    // 8KB
    __shared__ unsigned short Ws[64 * 64];    // 8KB

    int t = threadIdx.x;
    int w = t >> 6, lane = t & 63, g = lane >> 4, fr = lane & 15;
    int wm = w >> 1, wn = w & 1;              // wave tile 32 x 32

    f32x4 acc[2][2];
    for (int i = 0; i < 2; ++i)
        for (int j = 0; j < 2; ++j)
            acc[i][j] = (f32x4){0.f, 0.f, 0.f, 0.f};

    int boff = t * 16;

    for (int k0 = 0; k0 < DM; k0 += 64) {
        __syncthreads();
        for (int r = 0; r < 2; ++r) {
            int b = r * 4096 + boff;
            int row = b >> 7, colb = b & 127;
            gl_lds16(&A[(size_t)(i0 + row) * DM + k0 + (colb >> 1)],
                     (unsigned short*)((char*)As + b));
            gl_lds16(&W[(size_t)(j0 + row) * DM + k0 + (colb >> 1)],
                     (unsigned short*)((char*)Ws + b));
        }
        __syncthreads();
        for (int kk = 0; kk < 2; ++kk) {
            short8 af[2], wf[2];
            for (int it = 0; it < 2; ++it)
                af[it] = *(const short8*)&As[(wm * 32 + it * 16 + fr) * 64 + kk * 32 + g * 8];
            for (int jt = 0; jt < 2; ++jt)
                wf[jt] = *(const short8*)&Ws[(wn * 32 + jt * 16 + fr) * 64 + kk * 32 + g * 8];
            for (int it = 0; it < 2; ++it)
                for (int jt = 0; jt < 2; ++jt)
                    acc[it][jt] = __builtin_amdgcn_mfma_f32_16x16x32_bf16(af[it], wf[jt], acc[it][jt], 0, 0, 0);
        }
    }

    for (int jt = 0; jt < 2; ++jt) {
        int j = j0 + wn * 32 + jt * 16 + fr;
        float bv = bias[j];
        for (int it = 0; it < 2; ++it)
            for (int r = 0; r < 4; ++r) {
                int i = i0 + wm * 32 + it * 16 + g * 4 + r;
                f_out[(size_t)i * DM + j] = acc[it][jt][r] + bv;
            }
    }
}

// ---------------- flash attention, swapped-operand (lane owns q-column) ----------------
// 1024 blocks (4/CU), persistent waves, 8 per-XCD queues, fill interleaved (R5 lesson).
// QK^T computed as mfma(K,Q) -> lane (fr,g) owns S[k = kb+ktt*16+g*4+r][q = qbase+fr]:
//   - scores: direct f32x4 NT stores from C regs (16 full 64B lines / instr)
//   - softmax: in-lane over 16 k + shfl_xor(16,32); corr & 1/l lane-uniform
//   - P bf16 B-frag via per-wave XOR-swizzled LDS bounce (4x ds_write_b64 + 2x ds_read_b128)
//   - PV as O^T = mfma(V^T-frag, P-frag)
__global__ __launch_bounds__(256, 4) void attn_kernel(
    const unsigned short* q, const unsigned short* k, const unsigned short* vt,
    float* scores, unsigned short* attn, int* cnts)
{
    __shared__ unsigned short Pl[4][16 * 64];   // per-wave P (bf16), 128B rows, XOR-swizzled
    int w = threadIdx.x >> 6, lane = threadIdx.x & 63;
    int g = lane >> 4, fr = lane & 15;
    char* Pw = (char*)Pl[w];
    int swz = (fr & 7) << 4;
    int wr0 = fr * 128 + ((g * 8) ^ swz);             // ktt stride 32 bytes (XOR-safe: bits 4-6)
    int rd0 = fr * 128 + ((g * 16) ^ swz);            // B-frag chunk 0 (k 0..31)
    int rd1 = fr * 128 + ((64 + g * 16) ^ swz);       // B-frag chunk 1 (k 32..63)
    int xq = blockIdx.x & 7;
    int* cnt = cnts + xq * 16;

    for (;;) {
        int idx = 0;
        if (lane == 0) idx = atomicAdd(cnt, 1);
        idx = __shfl(idx, 0, 64);
        if (idx >= 384) break;

        int p = 127 - idx / 3;
        int bh = xq * 3 + idx % 3;
        int qbase = p * 16;
        int nt = (p >> 2) + 1;
        int b = bh / NH, h = bh % NH;
        int qg = qbase + fr;                  // this lane's q row

        const unsigned short* qp = q + (size_t)bh * S_LEN * HD;
        const unsigned short* kp = k + (size_t)bh * S_LEN * HD;
        const unsigned short* vp = vt + (size_t)bh * HD * S_LEN;
        float* sp = scores + (size_t)bh * S_LEN * S_LEN;

        short8 qf0 = *(const short8*)&qp[(size_t)qg * HD + g * 8];
        short8 qf1 = *(const short8*)&qp[(size_t)qg * HD + 32 + g * 8];

        f32x4 acc[4];
        for (int jt = 0; jt < 4; ++jt) acc[jt] = (f32x4){0.f, 0.f, 0.f, 0.f};
        float m_run = -1e30f, l_run = 0.f;

        for (int kt = 0; kt < nt; ++kt) {
            int kb = kt * 64;
            bool diag = (kt == nt - 1);
            // K fragments (A operand rows = k) and V^T fragments (A operand rows = d)
            short8 kf[4][2];
            for (int ktt = 0; ktt < 4; ++ktt) {
                kf[ktt][0] = *(const short8*)&kp[(size_t)(kb + ktt * 16 + fr) * HD + g * 8];
                kf[ktt][1] = *(const short8*)&kp[(size_t)(kb + ktt * 16 + fr) * HD + 32 + g * 8];
            }
            short8 vf[4][2];
            for (int jt = 0; jt < 4; ++jt) {
                vf[jt][0] = *(const short8*)&vp[(size_t)(jt * 16 + fr) * S_LEN + kb + g * 8];
                vf[jt][1] = *(const short8*)&vp[(size_t)(jt * 16 + fr) * S_LEN + kb + 32 + g * 8];
            }
            // QK^T swapped: S^T tile, lane owns col q=fr, rows k
            f32x4 s4v[4];
            __builtin_amdgcn_s_setprio(1);
            for (int ktt = 0; ktt < 4; ++ktt) {
                f32x4 s4 = (f32x4){0.f, 0.f, 0.f, 0.f};
                s4 = __builtin_amdgcn_mfma_f32_16x16x32_bf16(kf[ktt][0], qf0, s4, 0, 0, 0);
                s4 = __builtin_amdgcn_mfma_f32_16x16x32_bf16(kf[ktt][1], qf1, s4, 0, 0, 0);
                s4v[ktt] = s4;
            }
            __builtin_amdgcn_s_setprio(0);
            if (diag) {
                for (int ktt = 0; ktt < 4; ++ktt)
                    for (int r = 0; r < 4; ++r) {
                        int kg = kb + ktt * 16 + g * 4 + r;
                        if (kg > qg) s4v[ktt][r] = NEGINF;
                    }
            }
            // scores: direct NT stores (k-contiguous f32x4 per lane, row = q)
            for (int ktt = 0; ktt < 4; ++ktt)
                __builtin_nontemporal_store(s4v[ktt],
                    (f32x4*)&sp[(size_t)qg * S_LEN + kb + ktt * 16 + g * 4]);
            // online softmax, in-register (lane-uniform q)
            float tmax = s4v[0][0];
            for (int ktt = 0; ktt < 4; ++ktt)
                for (int r = 0; r < 4; ++r) tmax = fmaxf(tmax, s4v[ktt][r]);
            tmax = fmaxf(tmax, __shfl_xor(tmax, 16, 64));
            tmax = fmaxf(tmax, __shfl_xor(tmax, 32, 64));
            float m_new = fmaxf(m_run, tmax);
            float corr = __expf(m_run - m_new);
            float lsum = 0.f;
            for (int ktt = 0; ktt < 4; ++ktt)
                for (int r = 0; r < 4; ++r) {
                    float e = __expf(s4v[ktt][r] - m_new);
                    s4v[ktt][r] = e;
                    lsum += e;
                }
            lsum += __shfl_xor(lsum, 16, 64);
            lsum += __shfl_xor(lsum, 32, 64);
            l_run = l_run * corr + lsum;
            m_run = m_new;
            // rescale accumulator (corr lane-uniform: no shuffles)
            for (int jt = 0; jt < 4; ++jt)
                for (int r = 0; r < 4; ++r) acc[jt][r] *= corr;
            // P -> bf16 -> per-wave swizzled LDS (rows = q, cols = k)
            for (int ktt = 0; ktt < 4; ++ktt) {
                unsigned u0 = (unsigned)f2bf(s4v[ktt][0]) | ((unsigned)f2bf(s4v[ktt][1]) << 16);
                unsigned u1 = (unsigned)f2bf(s4v[ktt][2]) | ((unsigned)f2bf(s4v[ktt][3]) << 16);
                u32x2 uu = (u32x2){u0, u1};
                *(u32x2*)(Pw + (wr0 + ktt * 32)) = uu;
            }
            short8 pb0 = *(const short8*)(Pw + rd0);
            short8 pb1 = *(const short8*)(Pw + rd1);
            // PV: O^T += V^T . P   (C rows = d, cols = q)
            __builtin_amdgcn_s_setprio(1);
            for (int jt = 0; jt < 4; ++jt) {
                acc[jt] = __builtin_amdgcn_mfma_f32_16x16x32_bf16(vf[jt][0], pb0, acc[jt], 0, 0, 0);
                acc[jt] = __builtin_amdgcn_mfma_f32_16x16x32_bf16(vf[jt][1], pb1, acc[jt], 0, 0, 0);
            }
            __builtin_amdgcn_s_setprio(0);
        }
        // epilogue: O^T[d][q] -> attn[b*2048+q][h*64+d], 8B stores (d-contiguous)
        float linv = 1.0f / l_run;
        size_t arow = (size_t)(b * S_LEN + qg) * DM + h * HD;
        for (int jt = 0; jt < 4; ++jt) {
            short4v o;
            for (int r = 0; r < 4; ++r) o[r] = (short)f2bf(acc[jt][r] * linv);
            *(short4v*)&attn[arow + jt * 16 + g * 4] = o;
        }
        // NEG_INF fill for fully masked region (interleaved: hides under compute)
        f32x4 nv = (f32x4){NEGINF, NEGINF, NEGINF, NEGINF};
        int fill0 = nt * 64;
        for (int rr = 0; rr < 16; ++rr) {
            float* rowp = &sp[(size_t)(qbase + rr) * S_LEN];
            for (int c = fill0 + lane * 4; c < S_LEN; c += 256)
                __builtin_nontemporal_store(nv, (f32x4*)(rowp + c));
        }
    }
}

extern "C" void kernel_launch(void* const* d_in, const int* in_sizes, int n_in,
                              void* d_out, int out_size, void* d_ws, size_t ws_size,
                              hipStream_t stream) {
    const float* Q  = (const float*)d_in[0];
    const float* K  = (const float*)d_in[1];
    const float* V  = (const float*)d_in[2];
    // d_in[3] = mask (causal tril) — recomputed analytically, not read
    const float* Wq = (const float*)d_in[4];
    const float* bq = (const float*)d_in[5];
    const float* Wk = (const float*)d_in[6];
    const float* bk = (const float*)d_in[7];
    const float* Wv = (const float*)d_in[8];
    const float* bv = (const float*)d_in[9];
    const float* Wo = (const float*)d_in[10];
    const float* bo = (const float*)d_in[11];

    float* out = (float*)d_out;
    float* scores = out + (size_t)MROWS * DM;

    unsigned short* ws   = (unsigned short*)d_ws;
    unsigned short* Wbf  = ws;                              // 4 * WEL  (Wq,Wk,Wv,Wo bf16)
    unsigned short* qh   = Wbf + (size_t)4 * WEL;           // XEL q + XEL k (head-split) + XEL vt
    unsigned short* attn = qh + (size_t)3 * XEL;            // XEL attn bf16
    int* cnts            = (int*)(attn + (size_t)XEL);      // 8 queues x 16 ints

    cvt_w_kernel<<<dim3(288, 4), 256, 0, stream>>>(Wq, Wk, Wv, Wo, Wbf, cnts);
    gemm_qkv_kernel<<<dim3(192, 3), 256, 0, stream>>>(Q, K, V, Wbf, bq, bk, bv, qh);
    attn_kernel<<<dim3(1024), 256, 0, stream>>>(qh, qh + (size_t)XEL, qh + (size_t)2 * XEL,
                                                scores, attn, cnts);
    gemm_o_kernel<<<dim3(768), 256, 0, stream>>>(attn, Wbf + (size_t)3 * WEL, bo, out);
}

// Round 7
// 168.264 us; speedup vs baseline: 1.4573x; 1.4573x over previous
//
#include <hip/hip_runtime.h>
#include <hip/hip_bf16.h>

typedef __attribute__((ext_vector_type(8))) short short8;
typedef __attribute__((ext_vector_type(4))) short short4v;
typedef __attribute__((ext_vector_type(4))) float f32x4;

#define S_LEN 2048
#define DM 768
#define NH 12
#define HD 64
#define NB 2
#define MROWS (NB*S_LEN)          // 4096
#define NEGINF (-1.0e9f)
#define XEL 3145728               // 4096*768 elements
#define WEL 589824                // 768*768

__device__ __forceinline__ unsigned short f2bf(float x) {
    __hip_bfloat16 h = __float2bfloat16(x);   // RNE; compiler pairs into v_cvt_pk_bf16_f32
    return *reinterpret_cast<unsigned short*>(&h);
}

// async global->LDS, 16B per lane (wave-uniform base + lane*16 matches linear dest).
__device__ __forceinline__ void gl_lds16(const unsigned short* g, unsigned short* l) {
    __builtin_amdgcn_global_load_lds(
        (const __attribute__((address_space(1))) unsigned int*)g,
        (__attribute__((address_space(3))) unsigned int*)l, 16, 0, 0);
}

// ---------------- weights fp32 -> bf16 ----------------
__global__ __launch_bounds__(256) void cvt_w_kernel(
    const float* w0, const float* w1, const float* w2, const float* w3,
    unsigned short* dst)
{
    int which = blockIdx.y;
    const float* src = (which == 0) ? w0 : (which == 1) ? w1 : (which == 2) ? w2 : w3;
    size_t idx = (size_t)blockIdx.x * 256 + threadIdx.x;   // 0 .. WEL/8-1
    const float* s = src + idx * 8;
    f32x4 v0 = *(const f32x4*)s;
    f32x4 v1 = *(const f32x4*)(s + 4);
    short8 o;
    o[0] = (short)f2bf(v0[0]); o[1] = (short)f2bf(v0[1]);
    o[2] = (short)f2bf(v0[2]); o[3] = (short)f2bf(v0[3]);
    o[4] = (short)f2bf(v1[0]); o[5] = (short)f2bf(v1[1]);
    o[6] = (short)f2bf(v1[2]); o[7] = (short)f2bf(v1[3]);
    *(short8*)&dst[(size_t)which * WEL + idx * 8] = o;
}

// ---------------- QKV projection: C = X @ W^T + b, fused fp32->bf16 A-staging ----------------
// BM=128, BN=128. grid (192, 3). by 0 -> q (pre-scaled by 0.125); by 1 -> k; by 2 -> vt.
__global__ __launch_bounds__(256) void gemm_qkv_kernel(
    const float* Xq, const float* Xk, const float* Xv, const unsigned short* Wall,
    const float* b0, const float* b1, const float* b2, unsigned short* qh)
{
    int by = blockIdx.y;
    const float* A = (by == 0) ? Xq : (by == 1) ? Xk : Xv;
    const unsigned short* W = Wall + (size_t)by * WEL;
    const float* bias = (by == 0) ? b0 : (by == 1) ? b1 : b2;
    int bid = blockIdx.x;
    int im = bid & 31;      // 32 M tiles of 128
    int jn = bid >> 5;      // 6 N tiles of 128
    int i0 = im * 128, j0 = jn * 128;

    __shared__ unsigned short As[128 * 64];   // 16KB
    __shared__ unsigned short Ws[128 * 64];   // 16KB

    int t = threadIdx.x;
    int w = t >> 6, lane = t & 63, g = lane >> 4, fr = lane & 15;
    int wm = w >> 1, wn = w & 1;              // wave tile 64 x 64

    f32x4 acc[4][4];
    for (int i = 0; i < 4; ++i)
        for (int j = 0; j < 4; ++j)
            acc[i][j] = (f32x4){0.f, 0.f, 0.f, 0.f};

    int boff = t * 16;          // W staging byte offset per 4KB round
    int arow = t >> 3;          // A staging: 32 rows/round, 8 threads/row
    int acol = (t & 7) * 8;     // 8 floats per thread

    for (int k0 = 0; k0 < DM; k0 += 64) {
        __syncthreads();
        for (int r = 0; r < 4; ++r) {
            int b = r * 4096 + boff;
            int row = b >> 7, colb = b & 127;
            gl_lds16(&W[(size_t)(j0 + row) * DM + k0 + (colb >> 1)],
                     (unsigned short*)((char*)Ws + b));
        }
        for (int rr = 0; rr < 4; ++rr) {
            int row = rr * 32 + arow;
            const float* src = &A[(size_t)(i0 + row) * DM + k0 + acol];
            f32x4 v0 = *(const f32x4*)src;
            f32x4 v1 = *(const f32x4*)(src + 4);
            short8 o;
            o[0] = (short)f2bf(v0[0]); o[1] = (short)f2bf(v0[1]);
            o[2] = (short)f2bf(v0[2]); o[3] = (short)f2bf(v0[3]);
            o[4] = (short)f2bf(v1[0]); o[5] = (short)f2bf(v1[1]);
            o[6] = (short)f2bf(v1[2]); o[7] = (short)f2bf(v1[3]);
            *(short8*)&As[row * 64 + acol] = o;
        }
        __syncthreads();
        for (int kk = 0; kk < 2; ++kk) {
            short8 af[4], wf[4];
            for (int it = 0; it < 4; ++it)
                af[it] = *(const short8*)&As[(wm * 64 + it * 16 + fr) * 64 + kk * 32 + g * 8];
            for (int jt = 0; jt < 4; ++jt)
                wf[jt] = *(const short8*)&Ws[(wn * 64 + jt * 16 + fr) * 64 + kk * 32 + g * 8];
            for (int it = 0; it < 4; ++it)
                for (int jt = 0; jt < 4; ++jt)
                    acc[it][jt] = __builtin_amdgcn_mfma_f32_16x16x32_bf16(af[it], wf[jt], acc[it][jt], 0, 0, 0);
        }
    }

    float scl = (by == 0) ? 0.125f : 1.0f;    // fold 1/sqrt(64) into q (exact)
    if (by < 2) {
        unsigned short* outp = qh + (size_t)by * XEL;   // head-split [b][h][s][64]
        for (int jt = 0; jt < 4; ++jt) {
            int j = j0 + wn * 64 + jt * 16 + fr;
            float bv = bias[j];
            int h = j >> 6, dq = j & 63;
            for (int it = 0; it < 4; ++it)
                for (int r = 0; r < 4; ++r) {
                    int i = i0 + wm * 64 + it * 16 + g * 4 + r;
                    int bb = i >> 11, s = i & 2047;
                    outp[((size_t)((bb * NH + h) * S_LEN) + s) * HD + dq] = f2bf((acc[it][jt][r] + bv) * scl);
                }
        }
    } else {
        unsigned short* vtp = qh + (size_t)2 * XEL;     // V transposed [bh][64][s]
        for (int jt = 0; jt < 4; ++jt) {
            int j = j0 + wn * 64 + jt * 16 + fr;
            float bv = bias[j];
            int h = j >> 6, dq = j & 63;
            for (int it = 0; it < 4; ++it) {
                int ibase = i0 + wm * 64 + it * 16 + g * 4;
                int bb = ibase >> 11, s = ibase & 2047;
                short4v o;
                for (int r = 0; r < 4; ++r) o[r] = (short)f2bf(acc[it][jt][r] + bv);
                *(short4v*)&vtp[((size_t)(bb * NH + h) * HD + dq) * S_LEN + s] = o;
            }
        }
    }
}

// ---------------- out projection: BM=64, BN=64, 768 blocks (3/CU) ----------------
__global__ __launch_bounds__(256) void gemm_o_kernel(
    const unsigned short* A, const unsigned short* W, const float* bias, float* f_out)
{
    int bid = blockIdx.x;
    int im = bid & 63;      // 64 M tiles of 64
    int jn = bid >> 6;      // 12 N tiles of 64
    int i0 = im * 64, j0 = jn * 64;

    __shared__ unsigned short As[64 * 64];    // 8KB
    __shared__ unsigned short Ws[64 * 64];    // 8KB

    int t = threadIdx.x;
    int w = t >> 6, lane = t & 63, g = lane >> 4, fr = lane & 15;
    int wm = w >> 1, wn = w & 1;              // wave tile 32 x 32

    f32x4 acc[2][2];
    for (int i = 0; i < 2; ++i)
        for (int j = 0; j < 2; ++j)
            acc[i][j] = (f32x4){0.f, 0.f, 0.f, 0.f};

    int boff = t * 16;

    for (int k0 = 0; k0 < DM; k0 += 64) {
        __syncthreads();
        for (int r = 0; r < 2; ++r) {
            int b = r * 4096 + boff;
            int row = b >> 7, colb = b & 127;
            gl_lds16(&A[(size_t)(i0 + row) * DM + k0 + (colb >> 1)],
                     (unsigned short*)((char*)As + b));
            gl_lds16(&W[(size_t)(j0 + row) * DM + k0 + (colb >> 1)],
                     (unsigned short*)((char*)Ws + b));
        }
        __syncthreads();
        for (int kk = 0; kk < 2; ++kk) {
            short8 af[2], wf[2];
            for (int it = 0; it < 2; ++it)
                af[it] = *(const short8*)&As[(wm * 32 + it * 16 + fr) * 64 + kk * 32 + g * 8];
            for (int jt = 0; jt < 2; ++jt)
                wf[jt] = *(const short8*)&Ws[(wn * 32 + jt * 16 + fr) * 64 + kk * 32 + g * 8];
            for (int it = 0; it < 2; ++it)
                for (int jt = 0; jt < 2; ++jt)
                    acc[it][jt] = __builtin_amdgcn_mfma_f32_16x16x32_bf16(af[it], wf[jt], acc[it][jt], 0, 0, 0);
        }
    }

    for (int jt = 0; jt < 2; ++jt) {
        int j = j0 + wn * 32 + jt * 16 + fr;
        float bv = bias[j];
        for (int it = 0; it < 2; ++it)
            for (int r = 0; r < 4; ++r) {
                int i = i0 + wm * 32 + it * 16 + g * 4 + r;
                f_out[(size_t)i * DM + j] = acc[it][jt][r] + bv;
            }
    }
}

// ---------------- flash attention, block-cooperative LDS-staged K/V ----------------
// 768 blocks, static map: xcd=bid&7, slot=bid>>3; bh=xcd*3+slot%3, j=31-slot/3.
// Block = (bh, 64 q-rows). All 4 waves share nt=j+1 KV tiles, double-buffered in LDS.
// K/V staged via pre-swizzled GLOBAL source + linear global_load_lds (m173): LDS holds
// tile[row][colb ^ ((row&7)<<4)] -> frag ds_read_b128 is 2-way-conflict-free.
// Stores: every block writes exactly 64 rows x 2048 cols (computed + NEG_INF fill).
__global__ __launch_bounds__(256) void attn_kernel(
    const unsigned short* q, const unsigned short* k, const unsigned short* vt,
    float* scores, unsigned short* attn)
{
    __shared__ unsigned short KV[2][8192];   // [buf][0..4095]=K tile, [4096..]=V^T tile (swizzled)
    __shared__ float P[4][16][68];
    int t = threadIdx.x;
    int w = t >> 6, lane = t & 63, g = lane >> 4, fr = lane & 15;
    float (*Pw)[68] = P[w];

    int bid = blockIdx.x;
    int slot = bid >> 3;
    int bh = (bid & 7) * 3 + slot % 3;
    int j = 31 - slot / 3;
    int nt = j + 1;
    int qbase = j * 64 + w * 16;
    int b = bh / NH, h = bh % NH;

    const unsigned short* qp = q + (size_t)bh * S_LEN * HD;
    const unsigned short* kp = k + (size_t)bh * S_LEN * HD;
    const unsigned short* vp = vt + (size_t)bh * HD * S_LEN;
    float* sp = scores + (size_t)bh * S_LEN * S_LEN;

    // staging geometry: thread t covers LDS bytes t*16 of each 8KB tile-half round
    int srow2 = t >> 3;                 // 0..31
    int scb = (t & 7) * 16;             // byte col in 128B row

    short8 qf0 = *(const short8*)&qp[(size_t)(qbase + fr) * HD + g * 8];
    short8 qf1 = *(const short8*)&qp[(size_t)(qbase + fr) * HD + 32 + g * 8];

    f32x4 acc[4];
    for (int jt = 0; jt < 4; ++jt) acc[jt] = (f32x4){0.f, 0.f, 0.f, 0.f};
    float m_run = -1e30f, l_run = 0.f;

    int swzu = (fr & 7) * 8;            // swizzle in ushort units (bytes>>1)

    // prologue stage tile 0 into buf 0
    {
        for (int rd = 0; rd < 2; ++rd) {
            int row = rd * 32 + srow2;
            int sc = (scb ^ ((row & 7) << 4)) >> 1;      // ushort units
            gl_lds16(&kp[(size_t)row * HD + sc], &KV[0][(size_t)t * 8 + rd * 2048]);
            gl_lds16(&vp[(size_t)row * S_LEN + sc], &KV[0][4096 + (size_t)t * 8 + rd * 2048]);
        }
    }

    int buf = 0;
    for (int kt = 0; kt < nt; ++kt) {
        __syncthreads();   // stage of tile kt complete (vmcnt drained before barrier)
        if (kt + 1 < nt) {
            int kb2 = (kt + 1) * 64;
            for (int rd = 0; rd < 2; ++rd) {
                int row = rd * 32 + srow2;
                int sc = (scb ^ ((row & 7) << 4)) >> 1;
                gl_lds16(&kp[(size_t)(kb2 + row) * HD + sc], &KV[buf ^ 1][(size_t)t * 8 + rd * 2048]);
                gl_lds16(&vp[(size_t)row * S_LEN + kb2 + sc], &KV[buf ^ 1][4096 + (size_t)t * 8 + rd * 2048]);
            }
        }
        const unsigned short* Kb = KV[buf];
        const unsigned short* Vb = KV[buf] + 4096;
        int kb = kt * 64;
        bool diag = (kt == nt - 1);

        short8 kf[4][2];
        for (int ktt = 0; ktt < 4; ++ktt) {
            int base = (ktt * 16 + fr) * 64;
            kf[ktt][0] = *(const short8*)&Kb[base + ((g * 8) ^ swzu)];
            kf[ktt][1] = *(const short8*)&Kb[base + ((32 + g * 8) ^ swzu)];
        }
        __builtin_amdgcn_s_setprio(1);
        f32x4 s4v[4];
        for (int ktt = 0; ktt < 4; ++ktt) {
            f32x4 s4 = (f32x4){0.f, 0.f, 0.f, 0.f};
            s4 = __builtin_amdgcn_mfma_f32_16x16x32_bf16(qf0, kf[ktt][0], s4, 0, 0, 0);
            s4 = __builtin_amdgcn_mfma_f32_16x16x32_bf16(qf1, kf[ktt][1], s4, 0, 0, 0);
            s4v[ktt] = s4;
        }
        __builtin_amdgcn_s_setprio(0);
        if (diag) {
            for (int ktt = 0; ktt < 4; ++ktt) {
                int kg = kb + ktt * 16 + fr;     // C col = k index
                for (int r = 0; r < 4; ++r) {
                    int qg = qbase + g * 4 + r;  // C row = q index
                    float val = (kg <= qg) ? s4v[ktt][r] : NEGINF;
                    Pw[g * 4 + r][ktt * 16 + fr] = val;
                }
            }
        } else {
            for (int ktt = 0; ktt < 4; ++ktt)
                for (int r = 0; r < 4; ++r)
                    Pw[g * 4 + r][ktt * 16 + fr] = s4v[ktt][r];
        }
        // coalesced nontemporal scores write (16 rows x 64 cols fp32)
        for (int pass = 0; pass < 4; ++pass) {
            int rr = pass * 4 + g;
            int cc = fr * 4;
            f32x4 vv = *(const f32x4*)&Pw[rr][cc];
            __builtin_nontemporal_store(vv, (f32x4*)&sp[(size_t)(qbase + rr) * S_LEN + kb + cc]);
        }
        // online softmax in A-frag layout (lane owns q-row fr); vector LDS reads
        f32x4 pA = *(const f32x4*)&Pw[fr][g * 8];
        f32x4 pB = *(const f32x4*)&Pw[fr][g * 8 + 4];
        f32x4 pC = *(const f32x4*)&Pw[fr][32 + g * 8];
        f32x4 pD = *(const f32x4*)&Pw[fr][32 + g * 8 + 4];
        float pv[16];
        pv[0]=pA[0]; pv[1]=pA[1]; pv[2]=pA[2]; pv[3]=pA[3];
        pv[4]=pB[0]; pv[5]=pB[1]; pv[6]=pB[2]; pv[7]=pB[3];
        pv[8]=pC[0]; pv[9]=pC[1]; pv[10]=pC[2]; pv[11]=pC[3];
        pv[12]=pD[0]; pv[13]=pD[1]; pv[14]=pD[2]; pv[15]=pD[3];
        float tmax = pv[0];
        for (int e = 1; e < 16; ++e) tmax = fmaxf(tmax, pv[e]);
        tmax = fmaxf(tmax, __shfl_xor(tmax, 16, 64));
        tmax = fmaxf(tmax, __shfl_xor(tmax, 32, 64));
        float m_new = fmaxf(m_run, tmax);
        float corr = __expf(m_run - m_new);
        float lsum = 0.f;
        for (int e = 0; e < 16; ++e) { pv[e] = __expf(pv[e] - m_new); lsum += pv[e]; }
        lsum += __shfl_xor(lsum, 16, 64);
        lsum += __shfl_xor(lsum, 32, 64);
        l_run = l_run * corr + lsum;
        m_run = m_new;
        short8 pa0, pa1;
        for (int e = 0; e < 8; ++e) { pa0[e] = (short)f2bf(pv[e]); pa1[e] = (short)f2bf(pv[8 + e]); }
        float fc[4];
        for (int r = 0; r < 4; ++r) fc[r] = __shfl(corr, g * 4 + r, 64);
        for (int jt = 0; jt < 4; ++jt)
            for (int r = 0; r < 4; ++r) acc[jt][r] *= fc[r];
        short8 vf[4][2];
        for (int jt = 0; jt < 4; ++jt) {
            int base = (jt * 16 + fr) * 64;
            vf[jt][0] = *(const short8*)&Vb[base + ((g * 8) ^ swzu)];
            vf[jt][1] = *(const short8*)&Vb[base + ((32 + g * 8) ^ swzu)];
        }
        __builtin_amdgcn_s_setprio(1);
        for (int jt = 0; jt < 4; ++jt) {
            acc[jt] = __builtin_amdgcn_mfma_f32_16x16x32_bf16(pa0, vf[jt][0], acc[jt], 0, 0, 0);
            acc[jt] = __builtin_amdgcn_mfma_f32_16x16x32_bf16(pa1, vf[jt][1], acc[jt], 0, 0, 0);
        }
        __builtin_amdgcn_s_setprio(0);
        buf ^= 1;
    }
    // epilogue: divide by l, write attn bf16 [4096][768]
    float linv[4];
    for (int r = 0; r < 4; ++r) linv[r] = 1.0f / __shfl(l_run, g * 4 + r, 64);
    for (int jt = 0; jt < 4; ++jt) {
        int col = h * HD + jt * 16 + fr;
        for (int r = 0; r < 4; ++r) {
            int i = b * S_LEN + qbase + g * 4 + r;
            attn[(size_t)i * DM + col] = f2bf(acc[jt][r] * linv[r]);
        }
    }
    // NEG_INF fill for fully masked region (per wave, its 16 rows)
    f32x4 nv = (f32x4){NEGINF, NEGINF, NEGINF, NEGINF};
    int fill0 = nt * 64;
    for (int rr = 0; rr < 16; ++rr) {
        float* rowp = &sp[(size_t)(qbase + rr) * S_LEN];
        for (int c = fill0 + lane * 4; c < S_LEN; c += 256)
            __builtin_nontemporal_store(nv, (f32x4*)(rowp + c));
    }
}

extern "C" void kernel_launch(void* const* d_in, const int* in_sizes, int n_in,
                              void* d_out, int out_size, void* d_ws, size_t ws_size,
                              hipStream_t stream) {
    const float* Q  = (const float*)d_in[0];
    const float* K  = (const float*)d_in[1];
    const float* V  = (const float*)d_in[2];
    // d_in[3] = mask (causal tril) — recomputed analytically, not read
    const float* Wq = (const float*)d_in[4];
    const float* bq = (const float*)d_in[5];
    const float* Wk = (const float*)d_in[6];
    const float* bk = (const float*)d_in[7];
    const float* Wv = (const float*)d_in[8];
    const float* bv = (const float*)d_in[9];
    const float* Wo = (const float*)d_in[10];
    const float* bo = (const float*)d_in[11];

    float* out = (float*)d_out;
    float* scores = out + (size_t)MROWS * DM;

    unsigned short* ws   = (unsigned short*)d_ws;
    unsigned short* Wbf  = ws;                              // 4 * WEL  (Wq,Wk,Wv,Wo bf16)
    unsigned short* qh   = Wbf + (size_t)4 * WEL;           // XEL q + XEL k (head-split) + XEL vt
    unsigned short* attn = qh + (size_t)3 * XEL;            // XEL attn bf16

    cvt_w_kernel<<<dim3(288, 4), 256, 0, stream>>>(Wq, Wk, Wv, Wo, Wbf);
    gemm_qkv_kernel<<<dim3(192, 3), 256, 0, stream>>>(Q, K, V, Wbf, bq, bk, bv, qh);
    attn_kernel<<<dim3(768), 256, 0, stream>>>(qh, qh + (size_t)XEL, qh + (size_t)2 * XEL,
                                               scores, attn);
    gemm_o_kernel<<<dim3(768), 256, 0, stream>>>(attn, Wbf + (size_t)3 * WEL, bo, out);
}

// Round 8
// 157.499 us; speedup vs baseline: 1.5569x; 1.0684x over previous
//
#include <hip/hip_runtime.h>
#include <hip/hip_bf16.h>

typedef __attribute__((ext_vector_type(8))) short short8;
typedef __attribute__((ext_vector_type(4))) short short4v;
typedef __attribute__((ext_vector_type(4))) float f32x4;

#define S_LEN 2048
#define DM 768
#define NH 12
#define HD 64
#define NB 2
#define MROWS (NB*S_LEN)          // 4096
#define NEGINF (-1.0e9f)
#define XEL 3145728               // 4096*768 elements
#define WEL 589824                // 768*768

__device__ __forceinline__ unsigned short f2bf(float x) {
    __hip_bfloat16 h = __float2bfloat16(x);   // RNE; compiler pairs into v_cvt_pk_bf16_f32
    return *reinterpret_cast<unsigned short*>(&h);
}

// async global->LDS, 16B per lane (wave-uniform base + lane*16 matches linear dest).
__device__ __forceinline__ void gl_lds16(const unsigned short* g, unsigned short* l) {
    __builtin_amdgcn_global_load_lds(
        (const __attribute__((address_space(1))) unsigned int*)g,
        (__attribute__((address_space(3))) unsigned int*)l, 16, 0, 0);
}

// ---------------- weights fp32 -> bf16 ----------------
__global__ __launch_bounds__(256) void cvt_w_kernel(
    const float* w0, const float* w1, const float* w2, const float* w3,
    unsigned short* dst)
{
    int which = blockIdx.y;
    const float* src = (which == 0) ? w0 : (which == 1) ? w1 : (which == 2) ? w2 : w3;
    size_t idx = (size_t)blockIdx.x * 256 + threadIdx.x;   // 0 .. WEL/8-1
    const float* s = src + idx * 8;
    f32x4 v0 = *(const f32x4*)s;
    f32x4 v1 = *(const f32x4*)(s + 4);
    short8 o;
    o[0] = (short)f2bf(v0[0]); o[1] = (short)f2bf(v0[1]);
    o[2] = (short)f2bf(v0[2]); o[3] = (short)f2bf(v0[3]);
    o[4] = (short)f2bf(v1[0]); o[5] = (short)f2bf(v1[1]);
    o[6] = (short)f2bf(v1[2]); o[7] = (short)f2bf(v1[3]);
    *(short8*)&dst[(size_t)which * WEL + idx * 8] = o;
}

// ---------------- QKV projection: C = X @ W^T + b, fused fp32->bf16 A-staging ----------------
// BM=128, BN=128. grid (192, 3). XCD-coherent map: blocks sharing an A M-tile land on one
// XCD (xcd = bx%8 == im%8) so the 393KB fp32 A tile is read once from HBM, 5x from L2.
__global__ __launch_bounds__(256) void gemm_qkv_kernel(
    const float* Xq, const float* Xk, const float* Xv, const unsigned short* Wall,
    const float* b0, const float* b1, const float* b2, unsigned short* qh)
{
    int by = blockIdx.y;
    const float* A = (by == 0) ? Xq : (by == 1) ? Xk : Xv;
    const unsigned short* W = Wall + (size_t)by * WEL;
    const float* bias = (by == 0) ? b0 : (by == 1) ? b1 : b2;
    int bx = blockIdx.x;
    int im = (bx & 7) + 8 * (bx / 48);    // 32 M tiles of 128; im%8 == bx%8 (same XCD)
    int jn = (bx >> 3) % 6;               // 6 N tiles of 128
    int i0 = im * 128, j0 = jn * 128;

    __shared__ unsigned short As[128 * 64];   // 16KB
    __shared__ unsigned short Ws[128 * 64];   // 16KB

    int t = threadIdx.x;
    int w = t >> 6, lane = t & 63, g = lane >> 4, fr = lane & 15;
    int wm = w >> 1, wn = w & 1;              // wave tile 64 x 64

    f32x4 acc[4][4];
    for (int i = 0; i < 4; ++i)
        for (int j = 0; j < 4; ++j)
            acc[i][j] = (f32x4){0.f, 0.f, 0.f, 0.f};

    int boff = t * 16;          // W staging byte offset per 4KB round
    int arow = t >> 3;          // A staging: 32 rows/round, 8 threads/row
    int acol = (t & 7) * 8;     // 8 floats per thread

    for (int k0 = 0; k0 < DM; k0 += 64) {
        __syncthreads();
        for (int r = 0; r < 4; ++r) {
            int b = r * 4096 + boff;
            int row = b >> 7, colb = b & 127;
            gl_lds16(&W[(size_t)(j0 + row) * DM + k0 + (colb >> 1)],
                     (unsigned short*)((char*)Ws + b));
        }
        for (int rr = 0; rr < 4; ++rr) {
            int row = rr * 32 + arow;
            const float* src = &A[(size_t)(i0 + row) * DM + k0 + acol];
            f32x4 v0 = *(const f32x4*)src;
            f32x4 v1 = *(const f32x4*)(src + 4);
            short8 o;
            o[0] = (short)f2bf(v0[0]); o[1] = (short)f2bf(v0[1]);
            o[2] = (short)f2bf(v0[2]); o[3] = (short)f2bf(v0[3]);
            o[4] = (short)f2bf(v1[0]); o[5] = (short)f2bf(v1[1]);
            o[6] = (short)f2bf(v1[2]); o[7] = (short)f2bf(v1[3]);
            *(short8*)&As[row * 64 + acol] = o;
        }
        __syncthreads();
        for (int kk = 0; kk < 2; ++kk) {
            short8 af[4], wf[4];
            for (int it = 0; it < 4; ++it)
                af[it] = *(const short8*)&As[(wm * 64 + it * 16 + fr) * 64 + kk * 32 + g * 8];
            for (int jt = 0; jt < 4; ++jt)
                wf[jt] = *(const short8*)&Ws[(wn * 64 + jt * 16 + fr) * 64 + kk * 32 + g * 8];
            for (int it = 0; it < 4; ++it)
                for (int jt = 0; jt < 4; ++jt)
                    acc[it][jt] = __builtin_amdgcn_mfma_f32_16x16x32_bf16(af[it], wf[jt], acc[it][jt], 0, 0, 0);
        }
    }

    float scl = (by == 0) ? 0.125f : 1.0f;    // fold 1/sqrt(64) into q (exact)
    if (by < 2) {
        unsigned short* outp = qh + (size_t)by * XEL;   // head-split [b][h][s][64]
        for (int jt = 0; jt < 4; ++jt) {
            int j = j0 + wn * 64 + jt * 16 + fr;
            float bv = bias[j];
            int h = j >> 6, dq = j & 63;
            for (int it = 0; it < 4; ++it)
                for (int r = 0; r < 4; ++r) {
                    int i = i0 + wm * 64 + it * 16 + g * 4 + r;
                    int bb = i >> 11, s = i & 2047;
                    outp[((size_t)((bb * NH + h) * S_LEN) + s) * HD + dq] = f2bf((acc[it][jt][r] + bv) * scl);
                }
        }
    } else {
        unsigned short* vtp = qh + (size_t)2 * XEL;     // V transposed [bh][64][s]
        for (int jt = 0; jt < 4; ++jt) {
            int j = j0 + wn * 64 + jt * 16 + fr;
            float bv = bias[j];
            int h = j >> 6, dq = j & 63;
            for (int it = 0; it < 4; ++it) {
                int ibase = i0 + wm * 64 + it * 16 + g * 4;
                int bb = ibase >> 11, s = ibase & 2047;
                short4v o;
                for (int r = 0; r < 4; ++r) o[r] = (short)f2bf(acc[it][jt][r] + bv);
                *(short4v*)&vtp[((size_t)(bb * NH + h) * HD + dq) * S_LEN + s] = o;
            }
        }
    }
}

// ---------------- out projection: BM=64, BN=64, 768 blocks, XCD-coherent map ----------------
__global__ __launch_bounds__(256) void gemm_o_kernel(
    const unsigned short* A, const unsigned short* W, const float* bias, float* f_out)
{
    int bx = blockIdx.x;
    int im = (bx & 7) + 8 * (bx / 96);    // 64 M tiles of 64; same-A blocks share XCD
    int jn = (bx >> 3) % 12;              // 12 N tiles of 64
    int i0 = im * 64, j0 = jn * 64;

    __shared__ unsigned short As[64 * 64];    // 8KB
    __shared__ unsigned short Ws[64 * 64];    // 8KB

    int t = threadIdx.x;
    int w = t >> 6, lane = t & 63, g = lane >> 4, fr = lane & 15;
    int wm = w >> 1, wn = w & 1;              // wave tile 32 x 32

    f32x4 acc[2][2];
    for (int i = 0; i < 2; ++i)
        for (int j = 0; j < 2; ++j)
            acc[i][j] = (f32x4){0.f, 0.f, 0.f, 0.f};

    int boff = t * 16;

    for (int k0 = 0; k0 < DM; k0 += 64) {
        __syncthreads();
        for (int r = 0; r < 2; ++r) {
            int b = r * 4096 + boff;
            int row = b >> 7, colb = b & 127;
            gl_lds16(&A[(size_t)(i0 + row) * DM + k0 + (colb >> 1)],
                     (unsigned short*)((char*)As + b));
            gl_lds16(&W[(size_t)(j0 + row) * DM + k0 + (colb >> 1)],
                     (unsigned short*)((char*)Ws + b));
        }
        __syncthreads();
        for (int kk = 0; kk < 2; ++kk) {
            short8 af[2], wf[2];
            for (int it = 0; it < 2; ++it)
                af[it] = *(const short8*)&As[(wm * 32 + it * 16 + fr) * 64 + kk * 32 + g * 8];
            for (int jt = 0; jt < 2; ++jt)
                wf[jt] = *(const short8*)&Ws[(wn * 32 + jt * 16 + fr) * 64 + kk * 32 + g * 8];
            for (int it = 0; it < 2; ++it)
                for (int jt = 0; jt < 2; ++jt)
                    acc[it][jt] = __builtin_amdgcn_mfma_f32_16x16x32_bf16(af[it], wf[jt], acc[it][jt], 0, 0, 0);
        }
    }

    for (int jt = 0; jt < 2; ++jt) {
        int j = j0 + wn * 32 + jt * 16 + fr;
        float bv = bias[j];
        for (int it = 0; it < 2; ++it)
            for (int r = 0; r < 4; ++r) {
                int i = i0 + wm * 32 + it * 16 + g * 4 + r;
                f_out[(size_t)i * DM + j] = acc[it][jt][r] + bv;
            }
    }
}

// ---------------- flash attention, complementary-span pairing ----------------
// 768 blocks = 24 bh x 32 span-pairs. Block (bh, s): waves 0,1 -> light span s (32 q rows),
// waves 2,3 -> heavy span 63-s. nt_l + nt_h = 33 for every block -> uniform work AND uniform
// stores (exactly 64 rows x 2048 cols = 512 KB per block), independent of the CU map.
// K/V tiles staged once per block (double-buffered swizzled LDS); light waves keep helping
// stage + barrier after their compute ends.
__global__ __launch_bounds__(256) void attn_kernel(
    const unsigned short* q, const unsigned short* k, const unsigned short* vt,
    float* scores, unsigned short* attn)
{
    __shared__ unsigned short KV[2][8192];   // [buf][0..4095]=K tile, [4096..]=V^T tile (swizzled)
    __shared__ float P[4][16][68];
    int t = threadIdx.x;
    int w = t >> 6, lane = t & 63, g = lane >> 4, fr = lane & 15;
    float (*Pw)[68] = P[w];

    int bid = blockIdx.x;
    int bh = (bid & 7) * 3 + (bid >> 3) % 3;   // bh tied to XCD (K/V L2 locality)
    int s = bid / 24;                          // 0..31 pair index
    int myspan = (w < 2) ? s : 63 - s;
    int qbase = myspan * 32 + (w & 1) * 16;
    int myNt = ((myspan * 32 + 31) >> 6) + 1;
    int ntmax = (((63 - s) * 32 + 31) >> 6) + 1;
    int b = bh / NH, h = bh % NH;

    const unsigned short* qp = q + (size_t)bh * S_LEN * HD;
    const unsigned short* kp = k + (size_t)bh * S_LEN * HD;
    const unsigned short* vp = vt + (size_t)bh * HD * S_LEN;
    float* sp = scores + (size_t)bh * S_LEN * S_LEN;

    int srow2 = t >> 3;                 // 0..31
    int scb = (t & 7) * 16;             // byte col in 128B row
    int swzu = (fr & 7) * 8;            // frag-read swizzle in ushort units

    short8 qf0 = *(const short8*)&qp[(size_t)(qbase + fr) * HD + g * 8];
    short8 qf1 = *(const short8*)&qp[(size_t)(qbase + fr) * HD + 32 + g * 8];

    f32x4 acc[4];
    for (int jt = 0; jt < 4; ++jt) acc[jt] = (f32x4){0.f, 0.f, 0.f, 0.f};
    float m_run = -1e30f, l_run = 0.f;

    // prologue stage tile 0 into buf 0 (pre-swizzled global source, linear LDS dest)
    for (int rd = 0; rd < 2; ++rd) {
        int row = rd * 32 + srow2;
        int sc = (scb ^ ((row & 7) << 4)) >> 1;
        gl_lds16(&kp[(size_t)row * HD + sc], &KV[0][(size_t)t * 8 + rd * 2048]);
        gl_lds16(&vp[(size_t)row * S_LEN + sc], &KV[0][4096 + (size_t)t * 8 + rd * 2048]);
    }

    int buf = 0;
    for (int kt = 0; kt < ntmax; ++kt) {
        __syncthreads();   // staging of tile kt complete; prev compute's LDS reads done
        if (kt + 1 < ntmax) {
            int kb2 = (kt + 1) * 64;
            for (int rd = 0; rd < 2; ++rd) {
                int row = rd * 32 + srow2;
                int sc = (scb ^ ((row & 7) << 4)) >> 1;
                gl_lds16(&kp[(size_t)(kb2 + row) * HD + sc], &KV[buf ^ 1][(size_t)t * 8 + rd * 2048]);
                gl_lds16(&vp[(size_t)row * S_LEN + kb2 + sc], &KV[buf ^ 1][4096 + (size_t)t * 8 + rd * 2048]);
            }
        }
        if (kt < myNt) {
            const unsigned short* Kb = KV[buf];
            const unsigned short* Vb = KV[buf] + 4096;
            int kb = kt * 64;
            bool diag = (kt == myNt - 1);

            short8 kf[4][2];
            for (int ktt = 0; ktt < 4; ++ktt) {
                int base = (ktt * 16 + fr) * 64;
                kf[ktt][0] = *(const short8*)&Kb[base + ((g * 8) ^ swzu)];
                kf[ktt][1] = *(const short8*)&Kb[base + ((32 + g * 8) ^ swzu)];
            }
            __builtin_amdgcn_s_setprio(1);
            f32x4 s4v[4];
            for (int ktt = 0; ktt < 4; ++ktt) {
                f32x4 s4 = (f32x4){0.f, 0.f, 0.f, 0.f};
                s4 = __builtin_amdgcn_mfma_f32_16x16x32_bf16(qf0, kf[ktt][0], s4, 0, 0, 0);
                s4 = __builtin_amdgcn_mfma_f32_16x16x32_bf16(qf1, kf[ktt][1], s4, 0, 0, 0);
                s4v[ktt] = s4;
            }
            __builtin_amdgcn_s_setprio(0);
            if (diag) {
                for (int ktt = 0; ktt < 4; ++ktt) {
                    int kg = kb + ktt * 16 + fr;     // C col = k index
                    for (int r = 0; r < 4; ++r) {
                        int qg = qbase + g * 4 + r;  // C row = q index
                        float val = (kg <= qg) ? s4v[ktt][r] : NEGINF;
                        Pw[g * 4 + r][ktt * 16 + fr] = val;
                    }
                }
            } else {
                for (int ktt = 0; ktt < 4; ++ktt)
                    for (int r = 0; r < 4; ++r)
                        Pw[g * 4 + r][ktt * 16 + fr] = s4v[ktt][r];
            }
            // coalesced nontemporal scores write (16 rows x 64 cols fp32)
            for (int pass = 0; pass < 4; ++pass) {
                int rr = pass * 4 + g;
                int cc = fr * 4;
                f32x4 vv = *(const f32x4*)&Pw[rr][cc];
                __builtin_nontemporal_store(vv, (f32x4*)&sp[(size_t)(qbase + rr) * S_LEN + kb + cc]);
            }
            // online softmax in A-frag layout (lane owns q-row fr); vector LDS reads
            f32x4 pA = *(const f32x4*)&Pw[fr][g * 8];
            f32x4 pB = *(const f32x4*)&Pw[fr][g * 8 + 4];
            f32x4 pC = *(const f32x4*)&Pw[fr][32 + g * 8];
            f32x4 pD = *(const f32x4*)&Pw[fr][32 + g * 8 + 4];
            float pv[16];
            pv[0]=pA[0]; pv[1]=pA[1]; pv[2]=pA[2]; pv[3]=pA[3];
            pv[4]=pB[0]; pv[5]=pB[1]; pv[6]=pB[2]; pv[7]=pB[3];
            pv[8]=pC[0]; pv[9]=pC[1]; pv[10]=pC[2]; pv[11]=pC[3];
            pv[12]=pD[0]; pv[13]=pD[1]; pv[14]=pD[2]; pv[15]=pD[3];
            float tmax = pv[0];
            for (int e = 1; e < 16; ++e) tmax = fmaxf(tmax, pv[e]);
            tmax = fmaxf(tmax, __shfl_xor(tmax, 16, 64));
            tmax = fmaxf(tmax, __shfl_xor(tmax, 32, 64));
            float m_new = fmaxf(m_run, tmax);
            float corr = __expf(m_run - m_new);
            float lsum = 0.f;
            for (int e = 0; e < 16; ++e) { pv[e] = __expf(pv[e] - m_new); lsum += pv[e]; }
            lsum += __shfl_xor(lsum, 16, 64);
            lsum += __shfl_xor(lsum, 32, 64);
            l_run = l_run * corr + lsum;
            m_run = m_new;
            short8 pa0, pa1;
            for (int e = 0; e < 8; ++e) { pa0[e] = (short)f2bf(pv[e]); pa1[e] = (short)f2bf(pv[8 + e]); }
            float fc[4];
            for (int r = 0; r < 4; ++r) fc[r] = __shfl(corr, g * 4 + r, 64);
            for (int jt = 0; jt < 4; ++jt)
                for (int r = 0; r < 4; ++r) acc[jt][r] *= fc[r];
            short8 vf[4][2];
            for (int jt = 0; jt < 4; ++jt) {
                int base = (jt * 16 + fr) * 64;
                vf[jt][0] = *(const short8*)&Vb[base + ((g * 8) ^ swzu)];
                vf[jt][1] = *(const short8*)&Vb[base + ((32 + g * 8) ^ swzu)];
            }
            __builtin_amdgcn_s_setprio(1);
            for (int jt = 0; jt < 4; ++jt) {
                acc[jt] = __builtin_amdgcn_mfma_f32_16x16x32_bf16(pa0, vf[jt][0], acc[jt], 0, 0, 0);
                acc[jt] = __builtin_amdgcn_mfma_f32_16x16x32_bf16(pa1, vf[jt][1], acc[jt], 0, 0, 0);
            }
            __builtin_amdgcn_s_setprio(0);
        }
        buf ^= 1;
    }
    // epilogue: divide by l, write attn bf16 [4096][768]
    float linv[4];
    for (int r = 0; r < 4; ++r) linv[r] = 1.0f / __shfl(l_run, g * 4 + r, 64);
    for (int jt = 0; jt < 4; ++jt) {
        int col = h * HD + jt * 16 + fr;
        for (int r = 0; r < 4; ++r) {
            int i = b * S_LEN + qbase + g * 4 + r;
            attn[(size_t)i * DM + col] = f2bf(acc[jt][r] * linv[r]);
        }
    }
    // NEG_INF fill for this wave's fully masked region
    f32x4 nv = (f32x4){NEGINF, NEGINF, NEGINF, NEGINF};
    int fill0 = myNt * 64;
    for (int rr = 0; rr < 16; ++rr) {
        float* rowp = &sp[(size_t)(qbase + rr) * S_LEN];
        for (int c = fill0 + lane * 4; c < S_LEN; c += 256)
            __builtin_nontemporal_store(nv, (f32x4*)(rowp + c));
    }
}

extern "C" void kernel_launch(void* const* d_in, const int* in_sizes, int n_in,
                              void* d_out, int out_size, void* d_ws, size_t ws_size,
                              hipStream_t stream) {
    const float* Q  = (const float*)d_in[0];
    const float* K  = (const float*)d_in[1];
    const float* V  = (const float*)d_in[2];
    // d_in[3] = mask (causal tril) — recomputed analytically, not read
    const float* Wq = (const float*)d_in[4];
    const float* bq = (const float*)d_in[5];
    const float* Wk = (const float*)d_in[6];
    const float* bk = (const float*)d_in[7];
    const float* Wv = (const float*)d_in[8];
    const float* bv = (const float*)d_in[9];
    const float* Wo = (const float*)d_in[10];
    const float* bo = (const float*)d_in[11];

    float* out = (float*)d_out;
    float* scores = out + (size_t)MROWS * DM;

    unsigned short* ws   = (unsigned short*)d_ws;
    unsigned short* Wbf  = ws;                              // 4 * WEL  (Wq,Wk,Wv,Wo bf16)
    unsigned short* qh   = Wbf + (size_t)4 * WEL;           // XEL q + XEL k (head-split) + XEL vt
    unsigned short* attn = qh + (size_t)3 * XEL;            // XEL attn bf16

    cvt_w_kernel<<<dim3(288, 4), 256, 0, stream>>>(Wq, Wk, Wv, Wo, Wbf);
    gemm_qkv_kernel<<<dim3(192, 3), 256, 0, stream>>>(Q, K, V, Wbf, bq, bk, bv, qh);
    attn_kernel<<<dim3(768), 256, 0, stream>>>(qh, qh + (size_t)XEL, qh + (size_t)2 * XEL,
                                               scores, attn);
    gemm_o_kernel<<<dim3(768), 256, 0, stream>>>(attn, Wbf + (size_t)3 * WEL, bo, out);
}